// Round 2
// baseline (850.130 us; speedup 1.0000x reference)
//
#include <hip/hip_runtime.h>
#include <hip/hip_bf16.h>

// RG-LRU forward, MI355X/gfx950.
// I/O dtype: fp32 (reference is float32; comparison is done in bf16 domain at
// 2% tolerance). Internally: bf16 MFMA GEMMs, fp32 gate_a + fp32 scan state.
// Pipeline: convert x->bf16, transpose+convert weights -> GEMM1 (x@W_in+b) ->
// gate/elementwise kernel -> 3-pass chunked complex scan -> GEMM2 -> y, h_last.

typedef unsigned short u16;
typedef unsigned int u32;
typedef __attribute__((ext_vector_type(8))) short short8;
typedef __attribute__((ext_vector_type(4))) float floatx4;

#define DEV __device__ __forceinline__

DEV float bf2f(u16 u) { union { u32 i; float f; } v; v.i = ((u32)u) << 16; return v.f; }
DEV u16 f2bf(float f) {
  union { float f; u32 i; } v; v.f = f;
  u32 r = v.i + 0x7fffu + ((v.i >> 16) & 1u);  // RNE
  return (u16)(r >> 16);
}
DEV float sigmoidf_(float x) { return 1.f / (1.f + __expf(-x)); }

template <typename T> DEV T toOut(float v);
template <> DEV u16 toOut<u16>(float v) { return f2bf(v); }
template <> DEV float toOut<float>(float v) { return v; }

#if __has_builtin(__builtin_amdgcn_global_load_lds)
#define USE_ASYNC_LDS 1
#endif

DEV void cp16(const void* g, void* l) {
#if defined(USE_ASYNC_LDS) && defined(__HIP_DEVICE_COMPILE__)
  __builtin_amdgcn_global_load_lds((const __attribute__((address_space(1))) u32*)g,
                                   (__attribute__((address_space(3))) u32*)l, 16, 0, 0);
#else
  *(short8*)l = *(const short8*)g;
#endif
}
#define WAIT_VM() asm volatile("s_waitcnt vmcnt(0)" ::: "memory")

// ---------------------------------------------------------------- convert fp32 -> bf16
__global__ __launch_bounds__(256) void convert_f32_bf16(
    const float* __restrict__ src, u16* __restrict__ dst, long n) {
  long i = ((long)blockIdx.x * 256 + threadIdx.x) * 8;
  if (i >= n) return;
  float4 a = *(const float4*)(src + i);
  float4 b = *(const float4*)(src + i + 4);
  union { u16 u[8]; short8 v; } o;
  o.u[0] = f2bf(a.x); o.u[1] = f2bf(a.y); o.u[2] = f2bf(a.z); o.u[3] = f2bf(a.w);
  o.u[4] = f2bf(b.x); o.u[5] = f2bf(b.y); o.u[6] = f2bf(b.z); o.u[7] = f2bf(b.w);
  *(short8*)(dst + i) = o.v;
}

// ---------------------------------------------------------------- transpose + convert
// src: R x C row-major (fp32) -> dst: C x R row-major (bf16). batched via blockIdx.z.
__global__ __launch_bounds__(256) void transpose_f32_bf16(
    const float* __restrict__ src, u16* __restrict__ dst, int R, int C,
    long sBatch, long dBatch) {
  __shared__ u16 tile[32][33];
  const int n = blockIdx.z;
  src += (long)n * sBatch;
  dst += (long)n * dBatch;
  const int c0 = blockIdx.x * 32, r0 = blockIdx.y * 32;
  const int tx = threadIdx.x, ty = threadIdx.y;  // (32,8)
#pragma unroll
  for (int i = 0; i < 32; i += 8)
    tile[ty + i][tx] = f2bf(src[(long)(r0 + ty + i) * C + c0 + tx]);
  __syncthreads();
#pragma unroll
  for (int i = 0; i < 32; i += 8) dst[(long)(c0 + ty + i) * R + r0 + tx] = tile[tx][ty + i];
}

// ---------------------------------------------------------------- GEMM (m97 style)
// C[M,N] = A[M,K] @ BT[N,K]^T + bias[N]; A/BT bf16, bias fp32, out = OutT.
// 128x128 tile, 4 waves (2x2), each 64x64 = 4x4 subtiles of 16x16x32 MFMA.
template <typename OutT>
__global__ __launch_bounds__(256) void gemm_bt_bias(
    const u16* __restrict__ A, const u16* __restrict__ BT,
    const float* __restrict__ bias, OutT* __restrict__ C, int M, int N, int K) {
  __shared__ __align__(16) u16 As[128 * 64];
  __shared__ __align__(16) u16 Bs[128 * 64];
  const int nt = N >> 7;
  const int bm = blockIdx.x / nt, bn = blockIdx.x % nt;
  const int m0 = bm << 7, n0 = bn << 7;
  const int tid = threadIdx.x;
  const int lane = tid & 63, wid = tid >> 6;
  const int wm = (wid & 1) << 6, wn = (wid >> 1) << 6;
  const int lq = lane >> 4, lm = lane & 15;

  floatx4 acc[4][4];
#pragma unroll
  for (int i = 0; i < 4; ++i)
#pragma unroll
    for (int j = 0; j < 4; ++j) { acc[i][j].x = 0.f; acc[i][j].y = 0.f; acc[i][j].z = 0.f; acc[i][j].w = 0.f; }

  for (int kt = 0; kt < K; kt += 64) {
#pragma unroll
    for (int j = 0; j < 4; ++j) {  // A tile: 128 rows x 8 chunks of 16B
      int slot = (j << 8) + tid;
      int row = slot >> 3, ch = slot & 7;
      cp16(A + (size_t)(m0 + row) * K + kt + (ch << 3), (char*)As + slot * 16);
    }
#pragma unroll
    for (int j = 0; j < 4; ++j) {  // B tile
      int slot = (j << 8) + tid;
      int row = slot >> 3, ch = slot & 7;
      cp16(BT + (size_t)(n0 + row) * K + kt + (ch << 3), (char*)Bs + slot * 16);
    }
    WAIT_VM();
    __syncthreads();
#pragma unroll
    for (int kk = 0; kk < 64; kk += 32) {
      short8 af[4], bfr[4];
#pragma unroll
      for (int mi = 0; mi < 4; ++mi)
        af[mi] = *(const short8*)&As[(wm + mi * 16 + lm) * 64 + kk + lq * 8];
#pragma unroll
      for (int ni = 0; ni < 4; ++ni)
        bfr[ni] = *(const short8*)&Bs[(wn + ni * 16 + lm) * 64 + kk + lq * 8];
#pragma unroll
      for (int mi = 0; mi < 4; ++mi)
#pragma unroll
        for (int ni = 0; ni < 4; ++ni)
          acc[mi][ni] = __builtin_amdgcn_mfma_f32_16x16x32_bf16(af[mi], bfr[ni], acc[mi][ni], 0, 0, 0);
    }
    __syncthreads();
  }
  // C/D layout: col = lane&15, row = (lane>>4)*4 + reg (m89-verified)
#pragma unroll
  for (int ni = 0; ni < 4; ++ni) {
    int col = n0 + wn + ni * 16 + lm;
    float bv = bias[col];
#pragma unroll
    for (int mi = 0; mi < 4; ++mi) {
      int rbase = m0 + wm + mi * 16 + lq * 4;
#pragma unroll
      for (int r = 0; r < 4; ++r)
        C[(size_t)(rbase + r) * N + col] = toOut<OutT>(acc[mi][ni][r] + bv);
    }
  }
}

// ---------------------------------------------------------------- gates + elementwise
// Per (m-tile of 128 rows, block n of 8): MFMA tile M=128, N=256 (gx|ga), K=256.
// Epilogue exchanges gates through LDS (two 64-row halves, <=64KB), then computes
// sigmoid/log_a/norm and writes ga(f32), xr/xi(bf16).
__global__ __launch_bounds__(256) void gate_elem_kernel(
    const u16* __restrict__ xh, const u16* __restrict__ wgt,
    const float* __restrict__ bgx, const float* __restrict__ bga,
    const float* __restrict__ arp, const float* __restrict__ aip,
    float* __restrict__ ga_out, u16* __restrict__ xr_out, u16* __restrict__ xi_out) {
  __shared__ __align__(16) char smem[65536];
  u16* As = (u16*)smem;            // [128][64] during K-loop
  u16* Bs = (u16*)(smem + 16384);  // [256][64] during K-loop
  float* gates = (float*)smem;     // [64][256] during epilogue (aliased)

  const int m0 = blockIdx.x << 7;
  const int blk = blockIdx.y;
  const int tid = threadIdx.x;
  const int lane = tid & 63, wid = tid >> 6;
  const int wm = (wid & 1) << 6, wn = (wid >> 1) << 7;
  const int lq = lane >> 4, lm = lane & 15;

  floatx4 acc[4][8];
#pragma unroll
  for (int i = 0; i < 4; ++i)
#pragma unroll
    for (int j = 0; j < 8; ++j) { acc[i][j].x = 0.f; acc[i][j].y = 0.f; acc[i][j].z = 0.f; acc[i][j].w = 0.f; }

  const u16* Ag = xh + (size_t)m0 * 2048 + blk * 256;  // row stride 2048
  const u16* Bg = wgt + (size_t)blk * 65536;           // [256][256] row-major

  for (int kt = 0; kt < 256; kt += 64) {
#pragma unroll
    for (int j = 0; j < 4; ++j) {
      int slot = (j << 8) + tid;
      int row = slot >> 3, ch = slot & 7;
      cp16(Ag + (size_t)row * 2048 + kt + (ch << 3), (char*)As + slot * 16);
    }
#pragma unroll
    for (int j = 0; j < 8; ++j) {
      int slot = (j << 8) + tid;
      int row = slot >> 3, ch = slot & 7;
      cp16(Bg + (size_t)row * 256 + kt + (ch << 3), (char*)Bs + slot * 16);
    }
    WAIT_VM();
    __syncthreads();
#pragma unroll
    for (int kk = 0; kk < 64; kk += 32) {
      short8 af[4], bfr[8];
#pragma unroll
      for (int mi = 0; mi < 4; ++mi)
        af[mi] = *(const short8*)&As[(wm + mi * 16 + lm) * 64 + kk + lq * 8];
#pragma unroll
      for (int ni = 0; ni < 8; ++ni)
        bfr[ni] = *(const short8*)&Bs[(wn + ni * 16 + lm) * 64 + kk + lq * 8];
#pragma unroll
      for (int mi = 0; mi < 4; ++mi)
#pragma unroll
        for (int ni = 0; ni < 8; ++ni)
          acc[mi][ni] = __builtin_amdgcn_mfma_f32_16x16x32_bf16(af[mi], bfr[ni], acc[mi][ni], 0, 0, 0);
    }
    __syncthreads();
  }

  for (int half = 0; half < 2; ++half) {
    if ((wid & 1) == half) {  // waves owning rows [half*64, half*64+64)
#pragma unroll
      for (int mi = 0; mi < 4; ++mi)
#pragma unroll
        for (int ni = 0; ni < 8; ++ni)
#pragma unroll
          for (int r = 0; r < 4; ++r) {
            int row = mi * 16 + lq * 4 + r;  // 0..63 local
            int col = wn + ni * 16 + lm;     // 0..255
            gates[row * 256 + col] = acc[mi][ni][r];
          }
    }
    __syncthreads();
    for (int i = tid; i < 64 * 128; i += 256) {
      int row = i >> 7, ch = i & 127;
      size_t rowg = (size_t)m0 + half * 64 + row;
      int c = (blk << 7) + ch;
      float gx = sigmoidf_(gates[row * 256 + ch] + bgx[c]);
      float ga = sigmoidf_(gates[row * 256 + 128 + ch] + bga[c]);
      float sp = log1pf(__expf(arp[c]));  // softplus(a_real_param)
      float mag = __expf(-8.f * ga * sp);
      float norm = sqrtf(fmaxf(1.f - mag * mag, 0.f));
      ga_out[rowg * 1024 + c] = ga;  // fp32: scan precision requires it
      float f = norm * gx;
      xr_out[rowg * 1024 + c] = f2bf(f * bf2f(xh[rowg * 2048 + c]));
      xi_out[rowg * 1024 + c] = f2bf(f * bf2f(xh[rowg * 2048 + 1024 + c]));
    }
    __syncthreads();
  }
}

// ---------------------------------------------------------------- scan (chunk=64, 64 chunks)
// pass1: per (b,chunk,c) compute chunk aggregate (A,X) of h_t = a*h + x.
__global__ __launch_bounds__(256) void scan_pass1(
    const float* __restrict__ ga, const u16* __restrict__ xr, const u16* __restrict__ xi,
    const float* __restrict__ arp, const float* __restrict__ aip,
    float* __restrict__ Ar, float* __restrict__ Ai,
    float* __restrict__ Xr, float* __restrict__ Xi) {
  int tid = blockIdx.x * 256 + threadIdx.x;  // [0, 4*64*1024)
  int c = tid & 1023;
  int chunk = (tid >> 10) & 63;
  int b = tid >> 16;
  float sp = log1pf(__expf(arp[c]));
  float aim = aip[c];
  size_t base = ((size_t)b * 4096 + chunk * 64) * 1024 + c;
  float Arr = 1.f, Aii = 0.f, Xrr = 0.f, Xii = 0.f;
#pragma unroll 4
  for (int i = 0; i < 64; ++i) {
    size_t idx = base + (size_t)i * 1024;
    float g = ga[idx];
    float mag = __expf(-8.f * g * sp);
    float s, co;
    __sincosf(aim * g, &s, &co);
    float ar = mag * co, ai = mag * s;
    float nxr = ar * Xrr - ai * Xii + bf2f(xr[idx]);
    float nxi = ar * Xii + ai * Xrr + bf2f(xi[idx]);
    Xrr = nxr; Xii = nxi;
    float nar = ar * Arr - ai * Aii;
    float nai = ar * Aii + ai * Arr;
    Arr = nar; Aii = nai;
  }
  Ar[tid] = Arr; Ai[tid] = Aii; Xr[tid] = Xrr; Xi[tid] = Xii;
}

// pass2: exclusive scan of chunk aggregates along chunk dim per (b,c).
__global__ __launch_bounds__(256) void scan_pass2(
    const float* __restrict__ Ar, const float* __restrict__ Ai,
    const float* __restrict__ Xr, const float* __restrict__ Xi,
    float* __restrict__ Hr, float* __restrict__ Hi) {
  int tid = blockIdx.x * 256 + threadIdx.x;  // [0, 4096)
  int c = tid & 1023, b = tid >> 10;
  float hr = 0.f, hi = 0.f;
  for (int j = 0; j < 64; ++j) {
    int idx = (b << 16) + (j << 10) + c;
    Hr[idx] = hr; Hi[idx] = hi;
    float ar = Ar[idx], ai = Ai[idx];
    float nhr = ar * hr - ai * hi + Xr[idx];
    float nhi = ar * hi + ai * hr + Xi[idx];
    hr = nhr; hi = nhi;
  }
}

// pass3: replay chunk with incoming prefix; write h (bf16) and h_last (fp32).
__global__ __launch_bounds__(256) void scan_pass3(
    const float* __restrict__ ga, const u16* __restrict__ xr, const u16* __restrict__ xi,
    const float* __restrict__ arp, const float* __restrict__ aip,
    const float* __restrict__ Hr, const float* __restrict__ Hi,
    u16* __restrict__ h_out, float* __restrict__ tail) {
  int tid = blockIdx.x * 256 + threadIdx.x;
  int c = tid & 1023;
  int chunk = (tid >> 10) & 63;
  int b = tid >> 16;
  float sp = log1pf(__expf(arp[c]));
  float aim = aip[c];
  size_t row0 = (size_t)b * 4096 + chunk * 64;
  size_t base = row0 * 1024 + c;
  float hr = Hr[tid], hi = Hi[tid];
#pragma unroll 4
  for (int i = 0; i < 64; ++i) {
    size_t idx = base + (size_t)i * 1024;
    float g = ga[idx];
    float mag = __expf(-8.f * g * sp);
    float s, co;
    __sincosf(aim * g, &s, &co);
    float ar = mag * co, ai = mag * s;
    float nhr = ar * hr - ai * hi + bf2f(xr[idx]);
    float nhi = ar * hi + ai * hr + bf2f(xi[idx]);
    hr = nhr; hi = nhi;
    size_t r = row0 + i;
    h_out[r * 2048 + c] = f2bf(hr);
    h_out[r * 2048 + 1024 + c] = f2bf(hi);
  }
  if (chunk == 63) {  // s = 4095
    tail[(size_t)b * 2048 + c] = hr;
    tail[(size_t)b * 2048 + 1024 + c] = hi;
  }
}

// ---------------------------------------------------------------- launch
// ws layout (bytes); total ~215 MB. XB (bf16 x) aliases GA (dead until gates);
// h aliases x_h (dead after gates).
static const size_t OFF_XH = 0;            // u16 [16384][2048] (later: h)
static const size_t OFF_GA = 67108864;     // f32 [16384][1024]  (first: XB u16 [16384][2048])
static const size_t OFF_XR = 134217728;    // u16 [16384][1024]
static const size_t OFF_XI = 167772160;    // u16 [16384][1024]
static const size_t OFF_WIT = 201326592;   // u16 [2048][2048]  W_in^T
static const size_t OFF_WOT = 209715200;   // u16 [2048][2048]  W_out^T
static const size_t OFF_WGT = 218103808;   // u16 [8][256][256] gate weights^T (gx|ga)
static const size_t OFF_AGR = 219152384;   // f32 [262144] chunk aggregates
static const size_t OFF_AGI = 220200960;
static const size_t OFF_AXR = 221249536;
static const size_t OFF_AXI = 222298112;
static const size_t OFF_HPR = 223346688;   // f32 [262144] chunk prefixes
static const size_t OFF_HPI = 224395264;

extern "C" void kernel_launch(void* const* d_in, const int* in_sizes, int n_in,
                              void* d_out, int out_size, void* d_ws, size_t ws_size,
                              hipStream_t stream) {
  const float* x    = (const float*)d_in[0];
  const float* arp  = (const float*)d_in[1];
  const float* aip  = (const float*)d_in[2];
  const float* W_in = (const float*)d_in[3];
  const float* b_in = (const float*)d_in[4];
  const float* Wg_x = (const float*)d_in[5];
  const float* bg_x = (const float*)d_in[6];
  const float* Wg_a = (const float*)d_in[7];
  const float* bg_a = (const float*)d_in[8];
  const float* W_out = (const float*)d_in[9];
  const float* b_out = (const float*)d_in[10];

  char* ws = (char*)d_ws;
  u16* XH = (u16*)(ws + OFF_XH);
  u16* XB = (u16*)(ws + OFF_GA);   // bf16 copy of x; dead once GEMM1 finishes
  float* GA = (float*)(ws + OFF_GA);
  u16* XR = (u16*)(ws + OFF_XR);
  u16* XI = (u16*)(ws + OFF_XI);
  u16* WIT = (u16*)(ws + OFF_WIT);
  u16* WOT = (u16*)(ws + OFF_WOT);
  u16* WGT = (u16*)(ws + OFF_WGT);
  float* AGR = (float*)(ws + OFF_AGR);
  float* AGI = (float*)(ws + OFF_AGI);
  float* AXR = (float*)(ws + OFF_AXR);
  float* AXI = (float*)(ws + OFF_AXI);
  float* HPR = (float*)(ws + OFF_HPR);
  float* HPI = (float*)(ws + OFF_HPI);

  float* y_out = (float*)d_out;
  float* h_last = (float*)d_out + (size_t)16384 * 2048;

  // x -> bf16
  convert_f32_bf16<<<16384, 256, 0, stream>>>(x, XB, (long)16384 * 2048);

  dim3 tb(32, 8);
  // W_in (2048x2048 K-major) -> WIT (N-major, K contiguous), fp32 -> bf16
  transpose_f32_bf16<<<dim3(64, 64, 1), tb, 0, stream>>>(W_in, WIT, 2048, 2048, 0, 0);
  transpose_f32_bf16<<<dim3(64, 64, 1), tb, 0, stream>>>(W_out, WOT, 2048, 2048, 0, 0);
  // Wg_x[n]: 256x128 -> WGT[n][0:128][256] ; Wg_a[n] -> WGT[n][128:256][256]
  transpose_f32_bf16<<<dim3(4, 8, 8), tb, 0, stream>>>(Wg_x, WGT, 256, 128, 32768, 65536);
  transpose_f32_bf16<<<dim3(4, 8, 8), tb, 0, stream>>>(Wg_a, WGT + 32768, 256, 128, 32768, 65536);

  // x_h = x @ W_in + b_in  (bf16 out)
  gemm_bt_bias<u16><<<2048, 256, 0, stream>>>(XB, WIT, b_in, XH, 16384, 2048, 2048);
  // gates + a/x scan inputs (overwrites XB region with GA)
  gate_elem_kernel<<<dim3(128, 8), 256, 0, stream>>>(XH, WGT, bg_x, bg_a, arp, aip, GA, XR, XI);
  // chunked complex scan
  scan_pass1<<<1024, 256, 0, stream>>>(GA, XR, XI, arp, aip, AGR, AGI, AXR, AXI);
  scan_pass2<<<16, 256, 0, stream>>>(AGR, AGI, AXR, AXI, HPR, HPI);
  scan_pass3<<<1024, 256, 0, stream>>>(GA, XR, XI, arp, aip, HPR, HPI, XH /*h aliases x_h*/, h_last);
  // y = h @ W_out + b_out  (fp32 out)
  gemm_bt_bias<float><<<2048, 256, 0, stream>>>(XH, WOT, b_out, y_out, 16384, 2048, 2048);
}

// Round 3
// 817.641 us; speedup vs baseline: 1.0397x; 1.0397x over previous
//
#include <hip/hip_runtime.h>
#include <hip/hip_bf16.h>

// RG-LRU forward, MI355X/gfx950.
// I/O dtype: fp32. Internally bf16 MFMA GEMMs, fp32 gate_a + fp32 scan state.
// R2: XOR-swizzled LDS staging (conflict-free ds_read_b128 under
// global_load_lds's contiguous-dest constraint), in-register gate epilogue
// (gx/ga paired per lane; 48KB LDS), bm-fastest GEMM block order.

typedef unsigned short u16;
typedef unsigned int u32;
typedef __attribute__((ext_vector_type(8))) short short8;
typedef __attribute__((ext_vector_type(4))) float floatx4;

#define DEV __device__ __forceinline__

DEV float bf2f(u16 u) { union { u32 i; float f; } v; v.i = ((u32)u) << 16; return v.f; }
DEV u16 f2bf(float f) {
  union { float f; u32 i; } v; v.f = f;
  u32 r = v.i + 0x7fffu + ((v.i >> 16) & 1u);  // RNE
  return (u16)(r >> 16);
}
DEV float sigmoidf_(float x) { return 1.f / (1.f + __expf(-x)); }

template <typename T> DEV T toOut(float v);
template <> DEV u16 toOut<u16>(float v) { return f2bf(v); }
template <> DEV float toOut<float>(float v) { return v; }

#if __has_builtin(__builtin_amdgcn_global_load_lds)
#define USE_ASYNC_LDS 1
#endif

DEV void cp16(const void* g, void* l) {
#if defined(USE_ASYNC_LDS) && defined(__HIP_DEVICE_COMPILE__)
  __builtin_amdgcn_global_load_lds((const __attribute__((address_space(1))) u32*)g,
                                   (__attribute__((address_space(3))) u32*)l, 16, 0, 0);
#else
  *(short8*)l = *(const short8*)g;
#endif
}
#define WAIT_VM() asm volatile("s_waitcnt vmcnt(0)" ::: "memory")

// ---------------------------------------------------------------- convert fp32 -> bf16
__global__ __launch_bounds__(256) void convert_f32_bf16(
    const float* __restrict__ src, u16* __restrict__ dst, long n) {
  long i = ((long)blockIdx.x * 256 + threadIdx.x) * 8;
  if (i >= n) return;
  float4 a = *(const float4*)(src + i);
  float4 b = *(const float4*)(src + i + 4);
  union { u16 u[8]; short8 v; } o;
  o.u[0] = f2bf(a.x); o.u[1] = f2bf(a.y); o.u[2] = f2bf(a.z); o.u[3] = f2bf(a.w);
  o.u[4] = f2bf(b.x); o.u[5] = f2bf(b.y); o.u[6] = f2bf(b.z); o.u[7] = f2bf(b.w);
  *(short8*)(dst + i) = o.v;
}

// ---------------------------------------------------------------- transpose + convert
// src: R x C row-major (fp32) -> dst: C x R row-major (bf16). batched via blockIdx.z.
__global__ __launch_bounds__(256) void transpose_f32_bf16(
    const float* __restrict__ src, u16* __restrict__ dst, int R, int C,
    long sBatch, long dBatch) {
  __shared__ u16 tile[32][33];
  const int n = blockIdx.z;
  src += (long)n * sBatch;
  dst += (long)n * dBatch;
  const int c0 = blockIdx.x * 32, r0 = blockIdx.y * 32;
  const int tx = threadIdx.x, ty = threadIdx.y;  // (32,8)
#pragma unroll
  for (int i = 0; i < 32; i += 8)
    tile[ty + i][tx] = f2bf(src[(long)(r0 + ty + i) * C + c0 + tx]);
  __syncthreads();
#pragma unroll
  for (int i = 0; i < 32; i += 8) dst[(long)(c0 + ty + i) * R + r0 + tx] = tile[tx][ty + i];
}

// ---------------------------------------------------------------- GEMM (m97 + swizzle)
// C[M,N] = A[M,K] @ BT[N,K]^T + bias[N]; A/BT bf16, bias fp32, out = OutT.
// 128x128 tile, 4 waves (2x2), each 64x64 = 4x4 subtiles of 16x16x32 MFMA.
// LDS chunk column XOR-swizzled by (row&7): staging permutes the GLOBAL source
// chunk so the LDS destination stays contiguous (global_load_lds constraint);
// fragment reads then hit all 32 banks at <=2-way (free).
template <typename OutT>
__global__ __launch_bounds__(256) void gemm_bt_bias(
    const u16* __restrict__ A, const u16* __restrict__ BT,
    const float* __restrict__ bias, OutT* __restrict__ C, int M, int N, int K) {
  __shared__ __align__(16) u16 As[128 * 64];
  __shared__ __align__(16) u16 Bs[128 * 64];
  const int mt = M >> 7;
  const int bm = blockIdx.x % mt, bn = blockIdx.x / mt;  // bm fastest: share B-tile
  const int m0 = bm << 7, n0 = bn << 7;
  const int tid = threadIdx.x;
  const int lane = tid & 63, wid = tid >> 6;
  const int wm = (wid & 1) << 6, wn = (wid >> 1) << 6;
  const int lq = lane >> 4, lm = lane & 15;

  floatx4 acc[4][4];
#pragma unroll
  for (int i = 0; i < 4; ++i)
#pragma unroll
    for (int j = 0; j < 4; ++j) { acc[i][j].x = 0.f; acc[i][j].y = 0.f; acc[i][j].z = 0.f; acc[i][j].w = 0.f; }

  for (int kt = 0; kt < K; kt += 64) {
#pragma unroll
    for (int j = 0; j < 4; ++j) {  // A tile: 128 rows x 8 chunks of 16B
      int slot = (j << 8) + tid;
      int row = slot >> 3, ch = slot & 7;
      int gch = ch ^ (row & 7);  // swizzle: LDS slot ch holds global chunk gch
      cp16(A + (size_t)(m0 + row) * K + kt + (gch << 3), (char*)As + slot * 16);
    }
#pragma unroll
    for (int j = 0; j < 4; ++j) {  // B tile
      int slot = (j << 8) + tid;
      int row = slot >> 3, ch = slot & 7;
      int gch = ch ^ (row & 7);
      cp16(BT + (size_t)(n0 + row) * K + kt + (gch << 3), (char*)Bs + slot * 16);
    }
    WAIT_VM();
    __syncthreads();
#pragma unroll
    for (int kk = 0; kk < 64; kk += 32) {
      const int lc = (kk >> 3) + lq;  // logical chunk for this lane
      short8 af[4], bfr[4];
#pragma unroll
      for (int mi = 0; mi < 4; ++mi) {
        int r = wm + mi * 16 + lm;
        af[mi] = *(const short8*)&As[r * 64 + ((lc ^ (r & 7)) << 3)];
      }
#pragma unroll
      for (int ni = 0; ni < 4; ++ni) {
        int r = wn + ni * 16 + lm;
        bfr[ni] = *(const short8*)&Bs[r * 64 + ((lc ^ (r & 7)) << 3)];
      }
#pragma unroll
      for (int mi = 0; mi < 4; ++mi)
#pragma unroll
        for (int ni = 0; ni < 4; ++ni)
          acc[mi][ni] = __builtin_amdgcn_mfma_f32_16x16x32_bf16(af[mi], bfr[ni], acc[mi][ni], 0, 0, 0);
    }
    __syncthreads();
  }
  // C/D layout: col = lane&15, row = (lane>>4)*4 + reg (m89-verified)
#pragma unroll
  for (int ni = 0; ni < 4; ++ni) {
    int col = n0 + wn + ni * 16 + lm;
    float bv = bias[col];
#pragma unroll
    for (int mi = 0; mi < 4; ++mi) {
      int rbase = m0 + wm + mi * 16 + lq * 4;
#pragma unroll
      for (int r = 0; r < 4; ++r)
        C[(size_t)(rbase + r) * N + col] = toOut<OutT>(acc[mi][ni][r] + bv);
    }
  }
}

// ---------------------------------------------------------------- gates + elementwise
// Per (m-tile of 128 rows, blk of 8): MFMA tile M=128, N=256 (gx rows 0..127 of
// WGT^T, ga rows 128..255), K=256. Wave layout pairs gx/ga for the same output
// element in the SAME lane: wn=(wid>>1)*64; ni 0..3 -> gx cols wn+ni*16+lm,
// ni 4..7 -> ga cols 128+wn+(ni-4)*16+lm. Epilogue fully in-register.
__global__ __launch_bounds__(256, 2) void gate_elem_kernel(
    const u16* __restrict__ xh, const u16* __restrict__ wgt,
    const float* __restrict__ bgx, const float* __restrict__ bga,
    const float* __restrict__ arp,
    float* __restrict__ ga_out, u16* __restrict__ xr_out, u16* __restrict__ xi_out) {
  __shared__ __align__(16) u16 As[128 * 64];  // 16 KB
  __shared__ __align__(16) u16 Bs[256 * 64];  // 32 KB

  const int m0 = blockIdx.x << 7;
  const int blk = blockIdx.y;
  const int tid = threadIdx.x;
  const int lane = tid & 63, wid = tid >> 6;
  const int wm = (wid & 1) << 6, wn = (wid >> 1) << 6;
  const int lq = lane >> 4, lm = lane & 15;

  floatx4 acc[4][8];
#pragma unroll
  for (int i = 0; i < 4; ++i)
#pragma unroll
    for (int j = 0; j < 8; ++j) { acc[i][j].x = 0.f; acc[i][j].y = 0.f; acc[i][j].z = 0.f; acc[i][j].w = 0.f; }

  const u16* Ag = xh + (size_t)m0 * 2048 + blk * 256;  // row stride 2048
  const u16* Bg = wgt + (size_t)blk * 65536;           // [256][256] row-major

  for (int kt = 0; kt < 256; kt += 64) {
#pragma unroll
    for (int j = 0; j < 4; ++j) {
      int slot = (j << 8) + tid;
      int row = slot >> 3, ch = slot & 7;
      int gch = ch ^ (row & 7);
      cp16(Ag + (size_t)row * 2048 + kt + (gch << 3), (char*)As + slot * 16);
    }
#pragma unroll
    for (int j = 0; j < 8; ++j) {
      int slot = (j << 8) + tid;
      int row = slot >> 3, ch = slot & 7;
      int gch = ch ^ (row & 7);
      cp16(Bg + (size_t)row * 256 + kt + (gch << 3), (char*)Bs + slot * 16);
    }
    WAIT_VM();
    __syncthreads();
#pragma unroll
    for (int kk = 0; kk < 64; kk += 32) {
      const int lc = (kk >> 3) + lq;
      short8 af[4], bfr[8];
#pragma unroll
      for (int mi = 0; mi < 4; ++mi) {
        int r = wm + mi * 16 + lm;
        af[mi] = *(const short8*)&As[r * 64 + ((lc ^ (r & 7)) << 3)];
      }
#pragma unroll
      for (int ni = 0; ni < 8; ++ni) {
        int r = (ni < 4) ? (wn + ni * 16 + lm) : (128 + wn + (ni - 4) * 16 + lm);
        bfr[ni] = *(const short8*)&Bs[r * 64 + ((lc ^ (r & 7)) << 3)];
      }
#pragma unroll
      for (int mi = 0; mi < 4; ++mi)
#pragma unroll
        for (int ni = 0; ni < 8; ++ni)
          acc[mi][ni] = __builtin_amdgcn_mfma_f32_16x16x32_bf16(af[mi], bfr[ni], acc[mi][ni], 0, 0, 0);
    }
    __syncthreads();
  }

  // In-register epilogue: acc[mi][ni] = gx pre-act, acc[mi][ni+4] = ga pre-act
  // for element (row = wm+mi*16+lq*4+r, c = blk*128 + wn+ni*16+lm).
#pragma unroll
  for (int ni = 0; ni < 4; ++ni) {
    const int c = (blk << 7) + wn + ni * 16 + lm;
    const float bxv = bgx[c], bav = bga[c];
    const float sp = log1pf(__expf(arp[c]));  // softplus(a_real_param)
#pragma unroll
    for (int mi = 0; mi < 4; ++mi) {
      const size_t rowg0 = (size_t)m0 + wm + mi * 16 + lq * 4;
#pragma unroll
      for (int r = 0; r < 4; ++r) {
        const size_t rowg = rowg0 + r;
        float gxv = sigmoidf_(acc[mi][ni][r] + bxv);
        float gav = sigmoidf_(acc[mi][ni + 4][r] + bav);
        float mag = __expf(-8.f * gav * sp);
        float norm = sqrtf(fmaxf(1.f - mag * mag, 0.f));
        float f = norm * gxv;
        ga_out[rowg * 1024 + c] = gav;  // fp32: scan precision requires it
        xr_out[rowg * 1024 + c] = f2bf(f * bf2f(xh[rowg * 2048 + c]));
        xi_out[rowg * 1024 + c] = f2bf(f * bf2f(xh[rowg * 2048 + 1024 + c]));
      }
    }
  }
}

// ---------------------------------------------------------------- scan (chunk=64, 64 chunks)
// pass1: per (b,chunk,c) compute chunk aggregate (A,X) of h_t = a*h + x.
__global__ __launch_bounds__(256) void scan_pass1(
    const float* __restrict__ ga, const u16* __restrict__ xr, const u16* __restrict__ xi,
    const float* __restrict__ arp, const float* __restrict__ aip,
    float* __restrict__ Ar, float* __restrict__ Ai,
    float* __restrict__ Xr, float* __restrict__ Xi) {
  int tid = blockIdx.x * 256 + threadIdx.x;  // [0, 4*64*1024)
  int c = tid & 1023;
  int chunk = (tid >> 10) & 63;
  int b = tid >> 16;
  float sp = log1pf(__expf(arp[c]));
  float aim = aip[c];
  size_t base = ((size_t)b * 4096 + chunk * 64) * 1024 + c;
  float Arr = 1.f, Aii = 0.f, Xrr = 0.f, Xii = 0.f;
#pragma unroll 4
  for (int i = 0; i < 64; ++i) {
    size_t idx = base + (size_t)i * 1024;
    float g = ga[idx];
    float mag = __expf(-8.f * g * sp);
    float s, co;
    __sincosf(aim * g, &s, &co);
    float ar = mag * co, ai = mag * s;
    float nxr = ar * Xrr - ai * Xii + bf2f(xr[idx]);
    float nxi = ar * Xii + ai * Xrr + bf2f(xi[idx]);
    Xrr = nxr; Xii = nxi;
    float nar = ar * Arr - ai * Aii;
    float nai = ar * Aii + ai * Arr;
    Arr = nar; Aii = nai;
  }
  Ar[tid] = Arr; Ai[tid] = Aii; Xr[tid] = Xrr; Xi[tid] = Xii;
}

// pass2: exclusive scan of chunk aggregates along chunk dim per (b,c).
__global__ __launch_bounds__(256) void scan_pass2(
    const float* __restrict__ Ar, const float* __restrict__ Ai,
    const float* __restrict__ Xr, const float* __restrict__ Xi,
    float* __restrict__ Hr, float* __restrict__ Hi) {
  int tid = blockIdx.x * 256 + threadIdx.x;  // [0, 4096)
  int c = tid & 1023, b = tid >> 10;
  float hr = 0.f, hi = 0.f;
  for (int j = 0; j < 64; ++j) {
    int idx = (b << 16) + (j << 10) + c;
    Hr[idx] = hr; Hi[idx] = hi;
    float ar = Ar[idx], ai = Ai[idx];
    float nhr = ar * hr - ai * hi + Xr[idx];
    float nhi = ar * hi + ai * hr + Xi[idx];
    hr = nhr; hi = nhi;
  }
}

// pass3: replay chunk with incoming prefix; write h (bf16) and h_last (fp32).
__global__ __launch_bounds__(256) void scan_pass3(
    const float* __restrict__ ga, const u16* __restrict__ xr, const u16* __restrict__ xi,
    const float* __restrict__ arp, const float* __restrict__ aip,
    const float* __restrict__ Hr, const float* __restrict__ Hi,
    u16* __restrict__ h_out, float* __restrict__ tail) {
  int tid = blockIdx.x * 256 + threadIdx.x;
  int c = tid & 1023;
  int chunk = (tid >> 10) & 63;
  int b = tid >> 16;
  float sp = log1pf(__expf(arp[c]));
  float aim = aip[c];
  size_t row0 = (size_t)b * 4096 + chunk * 64;
  size_t base = row0 * 1024 + c;
  float hr = Hr[tid], hi = Hi[tid];
#pragma unroll 4
  for (int i = 0; i < 64; ++i) {
    size_t idx = base + (size_t)i * 1024;
    float g = ga[idx];
    float mag = __expf(-8.f * g * sp);
    float s, co;
    __sincosf(aim * g, &s, &co);
    float ar = mag * co, ai = mag * s;
    float nhr = ar * hr - ai * hi + bf2f(xr[idx]);
    float nhi = ar * hi + ai * hr + bf2f(xi[idx]);
    hr = nhr; hi = nhi;
    size_t r = row0 + i;
    h_out[r * 2048 + c] = f2bf(hr);
    h_out[r * 2048 + 1024 + c] = f2bf(hi);
  }
  if (chunk == 63) {  // s = 4095
    tail[(size_t)b * 2048 + c] = hr;
    tail[(size_t)b * 2048 + 1024 + c] = hi;
  }
}

// ---------------------------------------------------------------- launch
// ws layout (bytes); total ~215 MB. XB (bf16 x) aliases GA (dead until gates);
// h aliases x_h (dead after gates).
static const size_t OFF_XH = 0;            // u16 [16384][2048] (later: h)
static const size_t OFF_GA = 67108864;     // f32 [16384][1024]  (first: XB u16 [16384][2048])
static const size_t OFF_XR = 134217728;    // u16 [16384][1024]
static const size_t OFF_XI = 167772160;    // u16 [16384][1024]
static const size_t OFF_WIT = 201326592;   // u16 [2048][2048]  W_in^T
static const size_t OFF_WOT = 209715200;   // u16 [2048][2048]  W_out^T
static const size_t OFF_WGT = 218103808;   // u16 [8][256][256] gate weights^T (gx|ga)
static const size_t OFF_AGR = 219152384;   // f32 [262144] chunk aggregates
static const size_t OFF_AGI = 220200960;
static const size_t OFF_AXR = 221249536;
static const size_t OFF_AXI = 222298112;
static const size_t OFF_HPR = 223346688;   // f32 [262144] chunk prefixes
static const size_t OFF_HPI = 224395264;

extern "C" void kernel_launch(void* const* d_in, const int* in_sizes, int n_in,
                              void* d_out, int out_size, void* d_ws, size_t ws_size,
                              hipStream_t stream) {
  const float* x    = (const float*)d_in[0];
  const float* arp  = (const float*)d_in[1];
  const float* aip  = (const float*)d_in[2];
  const float* W_in = (const float*)d_in[3];
  const float* b_in = (const float*)d_in[4];
  const float* Wg_x = (const float*)d_in[5];
  const float* bg_x = (const float*)d_in[6];
  const float* Wg_a = (const float*)d_in[7];
  const float* bg_a = (const float*)d_in[8];
  const float* W_out = (const float*)d_in[9];
  const float* b_out = (const float*)d_in[10];

  char* ws = (char*)d_ws;
  u16* XH = (u16*)(ws + OFF_XH);
  u16* XB = (u16*)(ws + OFF_GA);   // bf16 copy of x; dead once GEMM1 finishes
  float* GA = (float*)(ws + OFF_GA);
  u16* XR = (u16*)(ws + OFF_XR);
  u16* XI = (u16*)(ws + OFF_XI);
  u16* WIT = (u16*)(ws + OFF_WIT);
  u16* WOT = (u16*)(ws + OFF_WOT);
  u16* WGT = (u16*)(ws + OFF_WGT);
  float* AGR = (float*)(ws + OFF_AGR);
  float* AGI = (float*)(ws + OFF_AGI);
  float* AXR = (float*)(ws + OFF_AXR);
  float* AXI = (float*)(ws + OFF_AXI);
  float* HPR = (float*)(ws + OFF_HPR);
  float* HPI = (float*)(ws + OFF_HPI);

  float* y_out = (float*)d_out;
  float* h_last = (float*)d_out + (size_t)16384 * 2048;

  // x -> bf16
  convert_f32_bf16<<<16384, 256, 0, stream>>>(x, XB, (long)16384 * 2048);

  dim3 tb(32, 8);
  // W_in (2048x2048 K-major) -> WIT (N-major, K contiguous), fp32 -> bf16
  transpose_f32_bf16<<<dim3(64, 64, 1), tb, 0, stream>>>(W_in, WIT, 2048, 2048, 0, 0);
  transpose_f32_bf16<<<dim3(64, 64, 1), tb, 0, stream>>>(W_out, WOT, 2048, 2048, 0, 0);
  // Wg_x[n]: 256x128 -> WGT[n][0:128][256] ; Wg_a[n] -> WGT[n][128:256][256]
  transpose_f32_bf16<<<dim3(4, 8, 8), tb, 0, stream>>>(Wg_x, WGT, 256, 128, 32768, 65536);
  transpose_f32_bf16<<<dim3(4, 8, 8), tb, 0, stream>>>(Wg_a, WGT + 32768, 256, 128, 32768, 65536);

  // x_h = x @ W_in + b_in  (bf16 out)
  gemm_bt_bias<u16><<<2048, 256, 0, stream>>>(XB, WIT, b_in, XH, 16384, 2048, 2048);
  // gates + a/x scan inputs (overwrites XB region with GA)
  gate_elem_kernel<<<dim3(128, 8), 256, 0, stream>>>(XH, WGT, bg_x, bg_a, arp, GA, XR, XI);
  // chunked complex scan
  scan_pass1<<<1024, 256, 0, stream>>>(GA, XR, XI, arp, aip, AGR, AGI, AXR, AXI);
  scan_pass2<<<16, 256, 0, stream>>>(AGR, AGI, AXR, AXI, HPR, HPI);
  scan_pass3<<<1024, 256, 0, stream>>>(GA, XR, XI, arp, aip, HPR, HPI, XH /*h aliases x_h*/, h_last);
  // y = h @ W_out + b_out  (fp32 out)
  gemm_bt_bias<float><<<2048, 256, 0, stream>>>(XH, WOT, b_out, y_out, 16384, 2048, 2048);
}